// Round 3
// baseline (231.275 us; speedup 1.0000x reference)
//
#include <hip/hip_runtime.h>

#define THRESH 0.7f

// Grid-stride, 1 element/lane (16B/lane contiguous on reg/rects), with
// reg/rects loads predicated on keep: ~70% of elements fail the threshold
// and need no box data (outputs are zeros). This drops the touched input
// working set from 168 MB to ~135 MB, putting inputs+outputs (~236 MB)
// under the 256 MB Infinity Cache instead of just over it (268 MB).
__global__ __launch_bounds__(256) void rnet_post_gs(
    const float2* __restrict__ cls,    // [M] (bg, face)
    const float4* __restrict__ reg,    // [M] dx1,dy1,dx2,dy2
    const float4* __restrict__ rects,  // [M] x1,y1,x2,y2
    const int*    __restrict__ hptr,
    const int*    __restrict__ wptr,
    float4* __restrict__ out_rects,    // [M]
    float*  __restrict__ out_scores,   // [M]
    float*  __restrict__ out_keep,     // [M]
    int M)
{
    const float fh = (float)*hptr;
    const float fw = (float)*wptr;
    const int stride = gridDim.x * blockDim.x;

    for (int i = blockIdx.x * blockDim.x + threadIdx.x; i < M; i += stride) {
        float2 c = cls[i];
        float score = c.y;
        bool k = score > THRESH;

        float4 o = make_float4(0.0f, 0.0f, 0.0f, 0.0f);
        float s = 0.0f;
        float kf = 0.0f;

        if (k) {  // exec-masked: lanes with keep==0 issue no requests
            float4 r = rects[i];
            float4 d = reg[i];
            float w = r.z - r.x;
            float h = r.w - r.y;
            o.x = fminf(fmaxf(fmaf(d.x, w, r.x), 0.0f), fw);
            o.y = fminf(fmaxf(fmaf(d.y, h, r.y), 0.0f), fh);
            o.z = fminf(fmaxf(fmaf(d.z, w, r.z), 0.0f), fw);
            o.w = fminf(fmaxf(fmaf(d.w, h, r.w), 0.0f), fh);
            s = score;
            kf = 1.0f;
        }

        out_rects[i]  = o;
        out_scores[i] = s;
        out_keep[i]   = kf;
    }
}

extern "C" void kernel_launch(void* const* d_in, const int* in_sizes, int n_in,
                              void* d_out, int out_size, void* d_ws, size_t ws_size,
                              hipStream_t stream) {
    const float2* cls   = (const float2*)d_in[0];  // classifier [B,N,2]
    const float4* reg   = (const float4*)d_in[1];  // bbox_regress [B,N,4]
    const float4* rects = (const float4*)d_in[2];  // input_rects [B,N,4]
    const int*    hptr  = (const int*)d_in[3];     // input_height scalar
    const int*    wptr  = (const int*)d_in[4];     // input_width scalar

    const int M = in_sizes[0] / 2;  // B*N

    float* out = (float*)d_out;
    float4* out_rects  = (float4*)out;        // 4*M floats
    float*  out_scores = out + 4ll * M;       // M floats
    float*  out_keep   = out + 5ll * M;       // M floats

    const int block = 256;
    // Persistent grid-stride: 16 blocks/CU nominal, 2x oversubscribed for
    // load balance under divergent skip.
    int grid = 4096;
    const int max_grid = (M + block - 1) / block;
    if (grid > max_grid) grid = max_grid;

    rnet_post_gs<<<grid, block, 0, stream>>>(cls, reg, rects, hptr, wptr,
                                             out_rects, out_scores, out_keep, M);
}

// Round 5
// 227.723 us; speedup vs baseline: 1.0156x; 1.0156x over previous
//
#include <hip/hip_runtime.h>

#define THRESH 0.7f

// ---------------------------------------------------------------------------
// Stream-split experiment: three prior structures (flat scalar, vec4 10-loads,
// predicated grid-stride) all pin at ~82 us / 2.2 TB/s. Testing whether the
// 6-concurrent-stream mix is what caps DRAM efficiency by splitting into two
// sequential kernels with fewer streams each.
// ---------------------------------------------------------------------------

// Kernel A: scores + keep only. 2 balanced streams (read cls, write s/k),
// all dwordx4. 4 elements per lane.
__global__ __launch_bounds__(256) void rnet_scores_keep(
    const float4* __restrict__ cls4,        // [M/2] two (bg,face) pairs per float4
    float4* __restrict__ out_scores4,       // [M/4]
    float4* __restrict__ out_keep4,         // [M/4]
    int M4)                                 // M/4
{
    int i = blockIdx.x * blockDim.x + threadIdx.x;
    if (i >= M4) return;

    float4 c01 = cls4[2l * i];
    float4 c23 = cls4[2l * i + 1];

    float s0 = c01.y, s1 = c01.w, s2 = c23.y, s3 = c23.w;
    float k0 = (s0 > THRESH) ? 1.0f : 0.0f;
    float k1 = (s1 > THRESH) ? 1.0f : 0.0f;
    float k2 = (s2 > THRESH) ? 1.0f : 0.0f;
    float k3 = (s3 > THRESH) ? 1.0f : 0.0f;

    out_scores4[i] = make_float4(s0 * k0, s1 * k1, s2 * k2, s3 * k3);
    out_keep4[i]   = make_float4(k0, k1, k2, k3);
}

// Kernel B: rects only. Reads cls (L3-hot after kernel A) to re-derive keep,
// reg/rects predicated on keep, writes out_rects. 4 streams.
__global__ __launch_bounds__(256) void rnet_rects(
    const float2* __restrict__ cls,    // [M]
    const float4* __restrict__ reg,    // [M]
    const float4* __restrict__ rects,  // [M]
    const int*    __restrict__ hptr,
    const int*    __restrict__ wptr,
    float4* __restrict__ out_rects,    // [M]
    int M)
{
    int i = blockIdx.x * blockDim.x + threadIdx.x;
    if (i >= M) return;

    const float fh = (float)*hptr;
    const float fw = (float)*wptr;

    float score = cls[i].y;
    float4 o = make_float4(0.0f, 0.0f, 0.0f, 0.0f);

    if (score > THRESH) {  // exec-masked: skipped lanes fetch no box lines
        float4 r = rects[i];
        float4 d = reg[i];
        float w = r.z - r.x;
        float h = r.w - r.y;
        o.x = fminf(fmaxf(fmaf(d.x, w, r.x), 0.0f), fw);
        o.y = fminf(fmaxf(fmaf(d.y, h, r.y), 0.0f), fh);
        o.z = fminf(fmaxf(fmaf(d.z, w, r.z), 0.0f), fw);
        o.w = fminf(fmaxf(fmaf(d.w, h, r.w), 0.0f), fh);
    }

    out_rects[i] = o;
}

// Fused fallback for M % 4 != 0 (round-3 structure).
__global__ __launch_bounds__(256) void rnet_post_fused(
    const float2* __restrict__ cls,
    const float4* __restrict__ reg,
    const float4* __restrict__ rects,
    const int*    __restrict__ hptr,
    const int*    __restrict__ wptr,
    float4* __restrict__ out_rects,
    float*  __restrict__ out_scores,
    float*  __restrict__ out_keep,
    int M)
{
    int i = blockIdx.x * blockDim.x + threadIdx.x;
    if (i >= M) return;

    const float fh = (float)*hptr;
    const float fw = (float)*wptr;

    float score = cls[i].y;
    bool k = score > THRESH;
    float4 o = make_float4(0.0f, 0.0f, 0.0f, 0.0f);
    float s = 0.0f, kf = 0.0f;

    if (k) {
        float4 r = rects[i];
        float4 d = reg[i];
        float w = r.z - r.x;
        float h = r.w - r.y;
        o.x = fminf(fmaxf(fmaf(d.x, w, r.x), 0.0f), fw);
        o.y = fminf(fmaxf(fmaf(d.y, h, r.y), 0.0f), fh);
        o.z = fminf(fmaxf(fmaf(d.z, w, r.z), 0.0f), fw);
        o.w = fminf(fmaxf(fmaf(d.w, h, r.w), 0.0f), fh);
        s = score;
        kf = 1.0f;
    }

    out_rects[i]  = o;
    out_scores[i] = s;
    out_keep[i]   = kf;
}

extern "C" void kernel_launch(void* const* d_in, const int* in_sizes, int n_in,
                              void* d_out, int out_size, void* d_ws, size_t ws_size,
                              hipStream_t stream) {
    const float*  clsf  = (const float*)d_in[0];   // classifier [B,N,2]
    const float4* reg   = (const float4*)d_in[1];  // bbox_regress [B,N,4]
    const float4* rects = (const float4*)d_in[2];  // input_rects [B,N,4]
    const int*    hptr  = (const int*)d_in[3];     // input_height scalar
    const int*    wptr  = (const int*)d_in[4];     // input_width scalar

    const int M = in_sizes[0] / 2;  // B*N

    float* out = (float*)d_out;
    float4* out_rects  = (float4*)out;        // 4*M floats
    float*  out_scores = out + 4ll * M;       // M floats
    float*  out_keep   = out + 5ll * M;       // M floats

    const int block = 256;

    if ((M & 3) == 0) {
        const int M4 = M >> 2;
        const int gridA = (M4 + block - 1) / block;
        rnet_scores_keep<<<gridA, block, 0, stream>>>(
            (const float4*)clsf, (float4*)out_scores, (float4*)out_keep, M4);

        const int gridB = (M + block - 1) / block;
        rnet_rects<<<gridB, block, 0, stream>>>(
            (const float2*)clsf, reg, rects, hptr, wptr, out_rects, M);
    } else {
        const int grid = (M + block - 1) / block;
        rnet_post_fused<<<grid, block, 0, stream>>>(
            (const float2*)clsf, reg, rects, hptr, wptr,
            out_rects, out_scores, out_keep, M);
    }
}